// Round 1
// baseline (559.137 us; speedup 1.0000x reference)
//
#include <hip/hip_runtime.h>
#include <hip/hip_bf16.h>

#define DMODEL 512   // D = H*DK = H*DV = 512

typedef __attribute__((ext_vector_type(8))) short bf16x8;
typedef __attribute__((ext_vector_type(4))) float f32x4;

__device__ inline void gload_lds16(const void* g, void* s) {
  // aux=2 -> NT (non-temporal): A is read exactly once, don't pollute L2
  __builtin_amdgcn_global_load_lds((const __attribute__((address_space(1))) void*)g,
                                   (__attribute__((address_space(3))) void*)s, 16, 0, 2);
}

__device__ inline float bflo(unsigned u) {
  union { float f; unsigned u; } c; c.u = u << 16; return c.f;
}
__device__ inline float bfhi(unsigned u) {
  union { float f; unsigned u; } c; c.u = u & 0xffff0000u; return c.f;
}

// ---------------------------------------------------------------------------
// Quad-persistent bf16 MFMA GEMM, W-streamed.
// Block = one 64-row quad: A-quad (64 KB, fragment-linear xp layout) staged to
// LDS ONCE (single barrier, NT-hinted), then 8 waves free-run. W is NOT
// staged: every block streams the same W fragments from global, L2-resident
// on all XCDs (0.5-1.5 MB) -- PROTECTED from eviction by writing C with
// non-temporal stores (the 50-75MB C stream was thrashing W to L3, exposing
// ~600cy latency per c-iter; that was the 19% MfmaUtil signature).
// Wp layout [stripe][c][n][lane][8]: a group's 4 tiles contiguous per c, so
// per c-iter the 4 B-loads share one base (+1KB offsets). 2-deep prefetch
// (3 rotating buffers, fully unrolled c-loop -> static indices) keeps 8 loads
// in flight per wave. __launch_bounds__(512,4) caps VGPR at 128 so LDS-limit
// (2 blocks/CU = 16 waves) stays the binding occupancy constraint.
// ---------------------------------------------------------------------------
template <bool OUT_BF16, int NT>
__global__ __launch_bounds__(512, 4)
void gemm_quad(const __hip_bfloat16* __restrict__ Ap,   // xp layout, 32768/quad
               const __hip_bfloat16* __restrict__ Wp,   // [stripe][c][n][lane][8]
               const float* __restrict__ bias, void* __restrict__ Cv,
               int Nrows, int ncols) {
  __shared__ __align__(16) short sA[32768];   // 64 KB: one quad of A
  const int tid = threadIdx.x;
  const int lane = tid & 63, w = tid >> 6;
  const int q = blockIdx.x;
  const __hip_bfloat16* Aq = Ap + (size_t)q * 32768;

#pragma unroll
  for (int i = 0; i < 8; ++i)
    gload_lds16(Aq + (size_t)(i * 512 + tid) * 8, &sA[(i * 512 + tid) * 8]);
  __syncthreads();

  const int l15 = lane & 15, lq = lane >> 4;

#pragma unroll 1
  for (int gs = 0; gs < NT / 4; ++gs) {
    const int ntb = w * NT + gs * 4;
    const int stripe = w * (NT / 4) + gs;
    const __hip_bfloat16* Wb = Wp + (size_t)stripe * 32768 + lane * 8;
    f32x4 acc[4][4] = {};
    bf16x8 b[3][4];

    // prologue: c=0 -> b[0], c=1 -> b[1]
#pragma unroll
    for (int n = 0; n < 4; ++n)
      b[0][n] = *(const bf16x8*)(Wb + (size_t)(0 * 4 + n) * 512);
#pragma unroll
    for (int n = 0; n < 4; ++n)
      b[1][n] = *(const bf16x8*)(Wb + (size_t)(1 * 4 + n) * 512);

#pragma unroll
    for (int c = 0; c < 16; ++c) {
      if (c + 2 < 16) {
        const int slot = (c + 2) % 3;           // compile-time after unroll
#pragma unroll
        for (int n = 0; n < 4; ++n)
          b[slot][n] = *(const bf16x8*)(Wb + (size_t)((c + 2) * 4 + n) * 512);
      }
      const int cs = c % 3;                     // compile-time after unroll
#pragma unroll
      for (int m = 0; m < 4; ++m) {
        bf16x8 af = *(const bf16x8*)&sA[(m * 16 + c) * 512 + lane * 8];
#pragma unroll
        for (int n = 0; n < 4; ++n)
          acc[m][n] = __builtin_amdgcn_mfma_f32_16x16x32_bf16(af, b[cs][n], acc[m][n], 0, 0, 0);
      }
    }

    // epilogue: C/D layout col=lane&15, row=quad*4+reg; NT stores (streaming,
    // never re-read through L2 -> keeps W resident)
#pragma unroll
    for (int m = 0; m < 4; ++m) {
      int rowb = q * 64 + m * 16;
#pragma unroll
      for (int n = 0; n < 4; ++n) {
        int col = (ntb + n) * 16 + l15;
        float bv = bias[col];
#pragma unroll
        for (int i = 0; i < 4; ++i) {
          int row = rowb + lq * 4 + i;
          if (row < Nrows) {
            float v = acc[m][n][i] + bv;
            if (OUT_BF16) {
              __hip_bfloat16 hv = __float2bfloat16(v);
              unsigned short us;
              __builtin_memcpy(&us, &hv, 2);
              __builtin_nontemporal_store(us, (unsigned short*)Cv + (size_t)row * ncols + col);
            } else {
              __builtin_nontemporal_store(v, (float*)Cv + (size_t)row * ncols + col);
            }
          }
        }
      }
    }
  }
}

// ---------------------------------------------------------------------------
// fp32 x -> bf16 xp permute: xp[t][c][lp][8], lp = q*16 + (r&15). Zero-pads.
// ---------------------------------------------------------------------------
__global__ void cvtp_kernel(const float* __restrict__ x, __hip_bfloat16* __restrict__ xp,
                            int Nrows, int NpadRows) {
  int tid = blockIdx.x * 256 + threadIdx.x;
  int r = tid >> 6, kb = tid & 63;
  if (r >= NpadRows) return;
  int t = r >> 4, c = kb >> 2, qq = kb & 3, lp = qq * 16 + (r & 15);
  __hip_bfloat16* dst = xp + (size_t)t * 8192 + c * 512 + lp * 8;
  union { ushort4 u[2]; __hip_bfloat16 h[8]; } o;
#pragma unroll
  for (int j = 0; j < 8; ++j) o.h[j] = __float2bfloat16(0.f);
  if (r < Nrows) {
    float4 v0 = *(const float4*)(x + (size_t)r * DMODEL + kb * 8);
    float4 v1 = *(const float4*)(x + (size_t)r * DMODEL + kb * 8 + 4);
    o.h[0] = __float2bfloat16(v0.x); o.h[1] = __float2bfloat16(v0.y);
    o.h[2] = __float2bfloat16(v0.z); o.h[3] = __float2bfloat16(v0.w);
    o.h[4] = __float2bfloat16(v1.x); o.h[5] = __float2bfloat16(v1.y);
    o.h[6] = __float2bfloat16(v1.z); o.h[7] = __float2bfloat16(v1.w);
  }
  *(ushort4*)dst = o.u[0];
  *(ushort4*)(dst + 4) = o.u[1];
}

// ---------------------------------------------------------------------------
// Weight permute: Wp[stripe][c][n][l][8] with stripe covering 4 n-tiles
// (col = (stripe*4+n)*16 + (l&15), k = c*32 + (l>>4)*8 + j). The 4 tiles of
// one c are CONTIGUOUS (4KB) so gemm's per-c loads share one base address.
// Stripes 0-23 -> Wp_qkv, 24-31 -> Wp_ff.
// ---------------------------------------------------------------------------
__global__ __launch_bounds__(256)
void wp_kernel(const float* __restrict__ Wk, const float* __restrict__ Wq,
               const float* __restrict__ Wv, const float* __restrict__ Wff,
               __hip_bfloat16* __restrict__ Wp_qkv, __hip_bfloat16* __restrict__ Wp_ff) {
  int c = blockIdx.x;        // 0..15
  int S = blockIdx.y;        // 0..31
  const float* W; __hip_bfloat16* dst;
  if (S < 8)       { W = Wk;  dst = Wp_qkv + (size_t)S * 32768; }
  else if (S < 16) { W = Wq;  dst = Wp_qkv + (size_t)S * 32768; }
  else if (S < 24) { W = Wv;  dst = Wp_qkv + (size_t)S * 32768; }
  else             { W = Wff; dst = Wp_ff + (size_t)(S - 24) * 32768; }
  int colbase = (S & 7) * 64;
  __shared__ float tile[32][64];
  for (int idx = threadIdx.x; idx < 2048; idx += 256) {
    int r = idx >> 6, col = idx & 63;
    tile[r][col] = W[(size_t)(c * 32 + r) * DMODEL + colbase + col];
  }
  __syncthreads();
  int n = threadIdx.x >> 6, l = threadIdx.x & 63;
  union { ushort4 u[2]; __hip_bfloat16 h[8]; } o;
#pragma unroll
  for (int j = 0; j < 8; ++j)
    o.h[j] = __float2bfloat16(tile[(l >> 4) * 8 + j][n * 16 + (l & 15)]);
  __hip_bfloat16* p = dst + ((size_t)(c * 4 + n) * 64 + l) * 8;
  *(ushort4*)p = o.u[0];
  *(ushort4*)(p + 4) = o.u[1];
}

// bias concat [bk | bq | bv]
__global__ void bias_kernel(const float* __restrict__ bk, const float* __restrict__ bq,
                            const float* __restrict__ bv, float* __restrict__ o) {
  int i = blockIdx.x * 256 + threadIdx.x;
  if (i < 512) o[i] = bk[i];
  else if (i < 1024) o[i] = bq[i - 512];
  else if (i < 1536) o[i] = bv[i - 1024];
}

// ---------------------------------------------------------------------------
// CSR build: histogram + parallel 3-phase scan + fill (stores SENDER directly)
// ---------------------------------------------------------------------------
__global__ void hist_kernel(const int* __restrict__ recv, int* __restrict__ deg, int M_) {
  int m = blockIdx.x * 256 + threadIdx.x;
  if (m < M_) atomicAdd(&deg[recv[m]], 1);
}

__global__ __launch_bounds__(256)
void scan_block(const int* __restrict__ deg, int* __restrict__ offs,
                int* __restrict__ bsum, int n) {
  __shared__ int sd[256];
  const int t = threadIdx.x;
  const int base = blockIdx.x * 1024;
  int v[4], s = 0;
#pragma unroll
  for (int j = 0; j < 4; ++j) {
    int idx = base + t * 4 + j;
    v[j] = (idx < n) ? deg[idx] : 0;
    s += v[j];
  }
  sd[t] = s;
  __syncthreads();
  for (int off = 1; off < 256; off <<= 1) {
    int x = (t >= off) ? sd[t - off] : 0;
    __syncthreads();
    sd[t] += x;
    __syncthreads();
  }
  int run = sd[t] - s;
#pragma unroll
  for (int j = 0; j < 4; ++j) {
    int idx = base + t * 4 + j;
    if (idx < n) offs[idx] = run;
    run += v[j];
  }
  if (t == 255) bsum[blockIdx.x] = sd[255];
}

__global__ void scan_mid(const int* __restrict__ bsum, int* __restrict__ bbase,
                         int nb, int* __restrict__ offs, int n) {
  int t = threadIdx.x;
  int x = (t < nb) ? bsum[t] : 0;
  int v = x;
  for (int off = 1; off < 64; off <<= 1) {
    int y = __shfl_up(v, off);
    if (t >= off) v += y;
  }
  if (t < nb) bbase[t] = v - x;
  if (t == nb - 1) offs[n] = v;
}

__global__ void scan_add(int* __restrict__ offs, const int* __restrict__ bbase,
                         int* __restrict__ cursor, int n) {
  int i = blockIdx.x * 256 + threadIdx.x;
  if (i < n) {
    int o = offs[i] + bbase[i >> 10];
    offs[i] = o;
    cursor[i] = o;
  }
}

__global__ void fill_kernel(const int* __restrict__ senders, const int* __restrict__ recv,
                            int* __restrict__ cursor, int* __restrict__ sidx, int M_) {
  int m = blockIdx.x * 256 + threadIdx.x;
  if (m < M_) {
    int pos = atomicAdd(&cursor[recv[m]], 1);
    sidx[pos] = senders[m];
  }
}

// ---------------------------------------------------------------------------
// Fused edge attention + aggregate, single pass, one wave per receiver.
// QKV row-major [K|Q|V] stride 1536 bf16. agg written directly in xp layout.
// ---------------------------------------------------------------------------
__global__ __launch_bounds__(256)
void attn_kernel(const __hip_bfloat16* __restrict__ QKV, const int* __restrict__ sidx,
                 const int* __restrict__ offs, __hip_bfloat16* __restrict__ aggp, int n) {
  const int lane = threadIdx.x & 63;
  const int wid  = threadIdx.x >> 6;
  const int r = blockIdx.x * 4 + wid;
  if (r >= n) return;
  const int start = offs[r];
  const int end   = offs[r + 1];

  uint4 qr = *(const uint4*)(QKV + (size_t)r * 1536 + 512 + lane * 8);
  float q[8] = {bflo(qr.x), bfhi(qr.x), bflo(qr.y), bfhi(qr.y),
                bflo(qr.z), bfhi(qr.z), bflo(qr.w), bfhi(qr.w)};

  float ssum = 0.f;
  float acc[8] = {};
  int e = start;
  for (; e + 2 <= end; e += 2) {
    int s0 = sidx[e], s1 = sidx[e + 1];
    const __hip_bfloat16* p0 = QKV + (size_t)s0 * 1536 + lane * 8;
    const __hip_bfloat16* p1 = QKV + (size_t)s1 * 1536 + lane * 8;
    uint4 k0 = *(const uint4*)p0;
    uint4 v0 = *(const uint4*)(p0 + 1024);
    uint4 k1 = *(const uint4*)p1;
    uint4 v1 = *(const uint4*)(p1 + 1024);
    float d0 = q[0] * bflo(k0.x) + q[1] * bfhi(k0.x) + q[2] * bflo(k0.y) + q[3] * bfhi(k0.y)
             + q[4] * bflo(k0.z) + q[5] * bfhi(k0.z) + q[6] * bflo(k0.w) + q[7] * bfhi(k0.w);
    float d1 = q[0] * bflo(k1.x) + q[1] * bfhi(k1.x) + q[2] * bflo(k1.y) + q[3] * bfhi(k1.y)
             + q[4] * bflo(k1.z) + q[5] * bfhi(k1.z) + q[6] * bflo(k1.w) + q[7] * bfhi(k1.w);
    d0 += __shfl_xor(d0, 1); d1 += __shfl_xor(d1, 1);
    d0 += __shfl_xor(d0, 2); d1 += __shfl_xor(d1, 2);
    d0 += __shfl_xor(d0, 4); d1 += __shfl_xor(d1, 4);
    float w0 = expf(d0 * 0.125f), w1 = expf(d1 * 0.125f);
    ssum += w0 + w1;
    acc[0] += w0 * bflo(v0.x) + w1 * bflo(v1.x);
    acc[1] += w0 * bfhi(v0.x) + w1 * bfhi(v1.x);
    acc[2] += w0 * bflo(v0.y) + w1 * bflo(v1.y);
    acc[3] += w0 * bfhi(v0.y) + w1 * bfhi(v1.y);
    acc[4] += w0 * bflo(v0.z) + w1 * bflo(v1.z);
    acc[5] += w0 * bfhi(v0.z) + w1 * bfhi(v1.z);
    acc[6] += w0 * bflo(v0.w) + w1 * bflo(v1.w);
    acc[7] += w0 * bfhi(v0.w) + w1 * bfhi(v1.w);
  }
  if (e < end) {
    int s0 = sidx[e];
    const __hip_bfloat16* p0 = QKV + (size_t)s0 * 1536 + lane * 8;
    uint4 k0 = *(const uint4*)p0;
    uint4 v0 = *(const uint4*)(p0 + 1024);
    float d0 = q[0] * bflo(k0.x) + q[1] * bfhi(k0.x) + q[2] * bflo(k0.y) + q[3] * bfhi(k0.y)
             + q[4] * bflo(k0.z) + q[5] * bfhi(k0.z) + q[6] * bflo(k0.w) + q[7] * bfhi(k0.w);
    d0 += __shfl_xor(d0, 1);
    d0 += __shfl_xor(d0, 2);
    d0 += __shfl_xor(d0, 4);
    float w0 = expf(d0 * 0.125f);
    ssum += w0;
    acc[0] += w0 * bflo(v0.x); acc[1] += w0 * bfhi(v0.x);
    acc[2] += w0 * bflo(v0.y); acc[3] += w0 * bfhi(v0.y);
    acc[4] += w0 * bflo(v0.z); acc[5] += w0 * bfhi(v0.z);
    acc[6] += w0 * bflo(v0.w); acc[7] += w0 * bfhi(v0.w);
  }
  const float inv = (end > start) ? 1.0f / ssum : 0.f;
  union { ushort4 u[2]; __hip_bfloat16 h[8]; } o;
#pragma unroll
  for (int j = 0; j < 8; ++j) o.h[j] = __float2bfloat16(acc[j] * inv);
  // xp layout: lane holds k=lane*8..+7 -> c=lane>>2, q=lane&3, lp=q*16+(r&15)
  int t = r >> 4, c = lane >> 2, qq = lane & 3, lp = qq * 16 + (r & 15);
  __hip_bfloat16* dst = aggp + (size_t)t * 8192 + c * 512 + lp * 8;
  *(ushort4*)dst = o.u[0];
  *(ushort4*)(dst + 4) = o.u[1];
}

// ---------------------------------------------------------------------------
// Launch
// ---------------------------------------------------------------------------
extern "C" void kernel_launch(void* const* d_in, const int* in_sizes, int n_in,
                              void* d_out, int out_size, void* d_ws, size_t ws_size,
                              hipStream_t stream) {
  const float* x    = (const float*)d_in[0];
  const int*   eidx = (const int*)d_in[1];
  const float* Wk   = (const float*)d_in[2];
  const float* bk   = (const float*)d_in[3];
  const float* Wq   = (const float*)d_in[4];
  const float* bq   = (const float*)d_in[5];
  const float* Wv   = (const float*)d_in[6];
  const float* bv   = (const float*)d_in[7];
  const float* Wff  = (const float*)d_in[8];
  const float* bff  = (const float*)d_in[9];
  float* out = (float*)d_out;

  const int N_ = in_sizes[0] / DMODEL;   // 25000
  const int M_ = in_sizes[1] / 2;        // 150000
  const int* senders = eidx;             // edge_index[0]
  const int* recv    = eidx + M_;        // edge_index[1]

  const int T16 = (N_ + 15) / 16;        // 16-row tiles
  const int Q4  = (T16 + 3) / 4;         // 64-row quads (= grid of gemm_quad)
  const int Npad = Q4 * 64;

  // workspace: xp | QKVb | aggp | Wp_qkv | Wp_ff | bqkv | ints
  __hip_bfloat16* xp    = (__hip_bfloat16*)d_ws;
  __hip_bfloat16* QKVb  = xp + (size_t)Npad * DMODEL;
  __hip_bfloat16* aggp  = QKVb + (size_t)N_ * 1536;
  __hip_bfloat16* Wp_qkv = aggp + (size_t)Npad * DMODEL;
  __hip_bfloat16* Wp_ff  = Wp_qkv + (size_t)24 * 32768;
  float* bqkv = (float*)(Wp_ff + (size_t)8 * 32768);
  int* deg    = (int*)(bqkv + 1536);
  int* offs   = deg + N_;
  int* cursor = offs + N_ + 1;
  int* sidx   = cursor + N_;
  int* bsum   = sidx + M_;
  int* bbase  = bsum + 64;

  const int nblk = (N_ + 1023) / 1024;   // <=64 for single-wave mid scan

  // conversions / permutes
  cvtp_kernel<<<(Npad * 64 + 255) / 256, 256, 0, stream>>>(x, xp, N_, Npad);
  wp_kernel<<<dim3(16, 32), 256, 0, stream>>>(Wk, Wq, Wv, Wff, Wp_qkv, Wp_ff);
  bias_kernel<<<6, 256, 0, stream>>>(bk, bq, bv, bqkv);

  // CSR build
  hipMemsetAsync(deg, 0, N_ * sizeof(int), stream);
  hist_kernel<<<(M_ + 255) / 256, 256, 0, stream>>>(recv, deg, M_);
  scan_block<<<nblk, 256, 0, stream>>>(deg, offs, bsum, N_);
  scan_mid<<<1, 64, 0, stream>>>(bsum, bbase, nblk, offs, N_);
  scan_add<<<(N_ + 255) / 256, 256, 0, stream>>>(offs, bbase, cursor, N_);
  fill_kernel<<<(M_ + 255) / 256, 256, 0, stream>>>(senders, recv, cursor, sidx, M_);

  // fused QKV projection: one block per quad, A-in-LDS, W streamed via L2
  gemm_quad<true, 12><<<Q4, 512, 0, stream>>>(xp, Wp_qkv, bqkv, QKVb, N_, 1536);

  // fused single-pass edge softmax + aggregate (writes aggp in xp layout)
  attn_kernel<<<(N_ + 3) / 4, 256, 0, stream>>>(QKVb, sidx, offs, aggp, N_);

  // output projection
  gemm_quad<false, 4><<<Q4, 512, 0, stream>>>(aggp, Wp_ff, bff, out, N_, DMODEL);
}

// Round 2
// 443.890 us; speedup vs baseline: 1.2596x; 1.2596x over previous
//
#include <hip/hip_runtime.h>
#include <hip/hip_bf16.h>

#define DMODEL 512   // D = H*DK = H*DV = 512

typedef __attribute__((ext_vector_type(8))) short bf16x8;
typedef __attribute__((ext_vector_type(4))) float f32x4;

__device__ inline void gload_lds16(const void* g, void* s) {
  __builtin_amdgcn_global_load_lds((const __attribute__((address_space(1))) void*)g,
                                   (__attribute__((address_space(3))) void*)s, 16, 0, 0);
}

__device__ inline float bflo(unsigned u) {
  union { float f; unsigned u; } c; c.u = u << 16; return c.f;
}
__device__ inline float bfhi(unsigned u) {
  union { float f; unsigned u; } c; c.u = u & 0xffff0000u; return c.f;
}

// ---------------------------------------------------------------------------
// Quad-persistent bf16 MFMA GEMM, W-streamed.
// Block = one 64-row quad: A-quad (64 KB, fragment-linear xp layout) staged to
// LDS ONCE (single barrier), then 8 waves free-run. W is NOT staged: every
// block streams the same W fragments from global (L2/L3-resident; round-0
// FETCH ~= A alone proves W never comes from HBM).
// ROUND-1 LESSON (counter-verified): NT stores on the 2B/lane epilogue caused
// 4.5x WRITE + 15x FETCH inflation (partial-line streaming writes -> RMW).
// Plain cached stores merge perfectly in L2 (WRITE ~= ideal 77MB). Keep plain.
// THIS ROUND: kill the per-c-iter vmcnt(0) drain. Round-0 copied b_nxt->b_cur
// each iter (forced full drain = one exposed L2/L3 round trip per 16 MFMAs).
// Now: Wp layout [stripe][c][n][lane][8] (a group's 4 tiles contiguous per c,
// one base + 1KB offsets) + 3-deep prefetch through 4 rotating buffers with
// the c-loop FULLY UNROLLED so all slot indices are compile-time (rule #20)
// and the compiler emits counted vmcnt(N) waits, keeping 12 loads in flight.
// ---------------------------------------------------------------------------
template <bool OUT_BF16, int NT>
__global__ __launch_bounds__(512, 2)
void gemm_quad(const __hip_bfloat16* __restrict__ Ap,   // xp layout, 32768/quad
               const __hip_bfloat16* __restrict__ Wp,   // [stripe][c][n][lane][8]
               const float* __restrict__ bias, void* __restrict__ Cv,
               int Nrows, int ncols) {
  __shared__ __align__(16) short sA[32768];   // 64 KB: one quad of A
  const int tid = threadIdx.x;
  const int lane = tid & 63, w = tid >> 6;
  const int q = blockIdx.x;
  const __hip_bfloat16* Aq = Ap + (size_t)q * 32768;

#pragma unroll
  for (int i = 0; i < 8; ++i)
    gload_lds16(Aq + (size_t)(i * 512 + tid) * 8, &sA[(i * 512 + tid) * 8]);
  __syncthreads();

  const int l15 = lane & 15, lq = lane >> 4;

#pragma unroll 1
  for (int gs = 0; gs < NT / 4; ++gs) {
    const int ntb = w * NT + gs * 4;
    const int stripe = w * (NT / 4) + gs;
    const __hip_bfloat16* Wb = Wp + (size_t)stripe * 32768 + lane * 8;
    f32x4 acc[4][4] = {};
    bf16x8 b[4][4];

    // prologue: c=0,1,2 -> slots 0,1,2
#pragma unroll
    for (int p = 0; p < 3; ++p)
#pragma unroll
      for (int n = 0; n < 4; ++n)
        b[p][n] = *(const bf16x8*)(Wb + (size_t)(p * 4 + n) * 512);

#pragma unroll
    for (int c = 0; c < 16; ++c) {
      if (c + 3 < 16) {
        const int slot = (c + 3) & 3;           // compile-time after unroll
#pragma unroll
        for (int n = 0; n < 4; ++n)
          b[slot][n] = *(const bf16x8*)(Wb + (size_t)((c + 3) * 4 + n) * 512);
      }
      const int cs = c & 3;                     // compile-time after unroll
#pragma unroll
      for (int m = 0; m < 4; ++m) {
        bf16x8 af = *(const bf16x8*)&sA[(m * 16 + c) * 512 + lane * 8];
#pragma unroll
        for (int n = 0; n < 4; ++n)
          acc[m][n] = __builtin_amdgcn_mfma_f32_16x16x32_bf16(af, b[cs][n], acc[m][n], 0, 0, 0);
      }
    }

    // epilogue: C/D layout col=lane&15, row=quad*4+reg. PLAIN stores: 32B/16-
    // lane segments merge to full lines in L2 (round-0 WRITE ~= ideal 77MB).
#pragma unroll
    for (int m = 0; m < 4; ++m) {
      int rowb = q * 64 + m * 16;
#pragma unroll
      for (int n = 0; n < 4; ++n) {
        int col = (ntb + n) * 16 + l15;
        float bv = bias[col];
#pragma unroll
        for (int i = 0; i < 4; ++i) {
          int row = rowb + lq * 4 + i;
          if (row < Nrows) {
            float v = acc[m][n][i] + bv;
            if (OUT_BF16)
              ((__hip_bfloat16*)Cv)[(size_t)row * ncols + col] = __float2bfloat16(v);
            else
              ((float*)Cv)[(size_t)row * ncols + col] = v;
          }
        }
      }
    }
  }
}

// ---------------------------------------------------------------------------
// fp32 x -> bf16 xp permute: xp[t][c][lp][8], lp = q*16 + (r&15). Zero-pads.
// ---------------------------------------------------------------------------
__global__ void cvtp_kernel(const float* __restrict__ x, __hip_bfloat16* __restrict__ xp,
                            int Nrows, int NpadRows) {
  int tid = blockIdx.x * 256 + threadIdx.x;
  int r = tid >> 6, kb = tid & 63;
  if (r >= NpadRows) return;
  int t = r >> 4, c = kb >> 2, qq = kb & 3, lp = qq * 16 + (r & 15);
  __hip_bfloat16* dst = xp + (size_t)t * 8192 + c * 512 + lp * 8;
  union { ushort4 u[2]; __hip_bfloat16 h[8]; } o;
#pragma unroll
  for (int j = 0; j < 8; ++j) o.h[j] = __float2bfloat16(0.f);
  if (r < Nrows) {
    float4 v0 = *(const float4*)(x + (size_t)r * DMODEL + kb * 8);
    float4 v1 = *(const float4*)(x + (size_t)r * DMODEL + kb * 8 + 4);
    o.h[0] = __float2bfloat16(v0.x); o.h[1] = __float2bfloat16(v0.y);
    o.h[2] = __float2bfloat16(v0.z); o.h[3] = __float2bfloat16(v0.w);
    o.h[4] = __float2bfloat16(v1.x); o.h[5] = __float2bfloat16(v1.y);
    o.h[6] = __float2bfloat16(v1.z); o.h[7] = __float2bfloat16(v1.w);
  }
  *(ushort4*)dst = o.u[0];
  *(ushort4*)(dst + 4) = o.u[1];
}

// ---------------------------------------------------------------------------
// Weight permute: Wp[stripe][c][n][l][8] with stripe covering 4 n-tiles
// (col = (stripe*4+n)*16 + (l&15), k = c*32 + (l>>4)*8 + j). The 4 tiles of
// one c are CONTIGUOUS (4KB) so gemm's per-c loads share one base address.
// Stripes 0-23 -> Wp_qkv, 24-31 -> Wp_ff.
// ---------------------------------------------------------------------------
__global__ __launch_bounds__(256)
void wp_kernel(const float* __restrict__ Wk, const float* __restrict__ Wq,
               const float* __restrict__ Wv, const float* __restrict__ Wff,
               __hip_bfloat16* __restrict__ Wp_qkv, __hip_bfloat16* __restrict__ Wp_ff) {
  int c = blockIdx.x;        // 0..15
  int S = blockIdx.y;        // 0..31
  const float* W; __hip_bfloat16* dst;
  if (S < 8)       { W = Wk;  dst = Wp_qkv + (size_t)S * 32768; }
  else if (S < 16) { W = Wq;  dst = Wp_qkv + (size_t)S * 32768; }
  else if (S < 24) { W = Wv;  dst = Wp_qkv + (size_t)S * 32768; }
  else             { W = Wff; dst = Wp_ff + (size_t)(S - 24) * 32768; }
  int colbase = (S & 7) * 64;
  __shared__ float tile[32][64];
  for (int idx = threadIdx.x; idx < 2048; idx += 256) {
    int r = idx >> 6, col = idx & 63;
    tile[r][col] = W[(size_t)(c * 32 + r) * DMODEL + colbase + col];
  }
  __syncthreads();
  int n = threadIdx.x >> 6, l = threadIdx.x & 63;
  union { ushort4 u[2]; __hip_bfloat16 h[8]; } o;
#pragma unroll
  for (int j = 0; j < 8; ++j)
    o.h[j] = __float2bfloat16(tile[(l >> 4) * 8 + j][n * 16 + (l & 15)]);
  __hip_bfloat16* p = dst + ((size_t)(c * 4 + n) * 64 + l) * 8;
  *(ushort4*)p = o.u[0];
  *(ushort4*)(p + 4) = o.u[1];
}

// bias concat [bk | bq | bv]
__global__ void bias_kernel(const float* __restrict__ bk, const float* __restrict__ bq,
                            const float* __restrict__ bv, float* __restrict__ o) {
  int i = blockIdx.x * 256 + threadIdx.x;
  if (i < 512) o[i] = bk[i];
  else if (i < 1024) o[i] = bq[i - 512];
  else if (i < 1536) o[i] = bv[i - 1024];
}

// ---------------------------------------------------------------------------
// CSR build: histogram + parallel 3-phase scan + fill (stores SENDER directly)
// ---------------------------------------------------------------------------
__global__ void hist_kernel(const int* __restrict__ recv, int* __restrict__ deg, int M_) {
  int m = blockIdx.x * 256 + threadIdx.x;
  if (m < M_) atomicAdd(&deg[recv[m]], 1);
}

__global__ __launch_bounds__(256)
void scan_block(const int* __restrict__ deg, int* __restrict__ offs,
                int* __restrict__ bsum, int n) {
  __shared__ int sd[256];
  const int t = threadIdx.x;
  const int base = blockIdx.x * 1024;
  int v[4], s = 0;
#pragma unroll
  for (int j = 0; j < 4; ++j) {
    int idx = base + t * 4 + j;
    v[j] = (idx < n) ? deg[idx] : 0;
    s += v[j];
  }
  sd[t] = s;
  __syncthreads();
  for (int off = 1; off < 256; off <<= 1) {
    int x = (t >= off) ? sd[t - off] : 0;
    __syncthreads();
    sd[t] += x;
    __syncthreads();
  }
  int run = sd[t] - s;
#pragma unroll
  for (int j = 0; j < 4; ++j) {
    int idx = base + t * 4 + j;
    if (idx < n) offs[idx] = run;
    run += v[j];
  }
  if (t == 255) bsum[blockIdx.x] = sd[255];
}

__global__ void scan_mid(const int* __restrict__ bsum, int* __restrict__ bbase,
                         int nb, int* __restrict__ offs, int n) {
  int t = threadIdx.x;
  int x = (t < nb) ? bsum[t] : 0;
  int v = x;
  for (int off = 1; off < 64; off <<= 1) {
    int y = __shfl_up(v, off);
    if (t >= off) v += y;
  }
  if (t < nb) bbase[t] = v - x;
  if (t == nb - 1) offs[n] = v;
}

__global__ void scan_add(int* __restrict__ offs, const int* __restrict__ bbase,
                         int* __restrict__ cursor, int n) {
  int i = blockIdx.x * 256 + threadIdx.x;
  if (i < n) {
    int o = offs[i] + bbase[i >> 10];
    offs[i] = o;
    cursor[i] = o;
  }
}

__global__ void fill_kernel(const int* __restrict__ senders, const int* __restrict__ recv,
                            int* __restrict__ cursor, int* __restrict__ sidx, int M_) {
  int m = blockIdx.x * 256 + threadIdx.x;
  if (m < M_) {
    int pos = atomicAdd(&cursor[recv[m]], 1);
    sidx[pos] = senders[m];
  }
}

// ---------------------------------------------------------------------------
// Fused edge attention + aggregate, single pass, one wave per receiver.
// QKV row-major [K|Q|V] stride 1536 bf16. agg written directly in xp layout.
// ---------------------------------------------------------------------------
__global__ __launch_bounds__(256)
void attn_kernel(const __hip_bfloat16* __restrict__ QKV, const int* __restrict__ sidx,
                 const int* __restrict__ offs, __hip_bfloat16* __restrict__ aggp, int n) {
  const int lane = threadIdx.x & 63;
  const int wid  = threadIdx.x >> 6;
  const int r = blockIdx.x * 4 + wid;
  if (r >= n) return;
  const int start = offs[r];
  const int end   = offs[r + 1];

  uint4 qr = *(const uint4*)(QKV + (size_t)r * 1536 + 512 + lane * 8);
  float q[8] = {bflo(qr.x), bfhi(qr.x), bflo(qr.y), bfhi(qr.y),
                bflo(qr.z), bfhi(qr.z), bflo(qr.w), bfhi(qr.w)};

  float ssum = 0.f;
  float acc[8] = {};
  int e = start;
  for (; e + 2 <= end; e += 2) {
    int s0 = sidx[e], s1 = sidx[e + 1];
    const __hip_bfloat16* p0 = QKV + (size_t)s0 * 1536 + lane * 8;
    const __hip_bfloat16* p1 = QKV + (size_t)s1 * 1536 + lane * 8;
    uint4 k0 = *(const uint4*)p0;
    uint4 v0 = *(const uint4*)(p0 + 1024);
    uint4 k1 = *(const uint4*)p1;
    uint4 v1 = *(const uint4*)(p1 + 1024);
    float d0 = q[0] * bflo(k0.x) + q[1] * bfhi(k0.x) + q[2] * bflo(k0.y) + q[3] * bfhi(k0.y)
             + q[4] * bflo(k0.z) + q[5] * bfhi(k0.z) + q[6] * bflo(k0.w) + q[7] * bfhi(k0.w);
    float d1 = q[0] * bflo(k1.x) + q[1] * bfhi(k1.x) + q[2] * bflo(k1.y) + q[3] * bfhi(k1.y)
             + q[4] * bflo(k1.z) + q[5] * bfhi(k1.z) + q[6] * bflo(k1.w) + q[7] * bfhi(k1.w);
    d0 += __shfl_xor(d0, 1); d1 += __shfl_xor(d1, 1);
    d0 += __shfl_xor(d0, 2); d1 += __shfl_xor(d1, 2);
    d0 += __shfl_xor(d0, 4); d1 += __shfl_xor(d1, 4);
    float w0 = expf(d0 * 0.125f), w1 = expf(d1 * 0.125f);
    ssum += w0 + w1;
    acc[0] += w0 * bflo(v0.x) + w1 * bflo(v1.x);
    acc[1] += w0 * bfhi(v0.x) + w1 * bfhi(v1.x);
    acc[2] += w0 * bflo(v0.y) + w1 * bflo(v1.y);
    acc[3] += w0 * bfhi(v0.y) + w1 * bfhi(v1.y);
    acc[4] += w0 * bflo(v0.z) + w1 * bflo(v1.z);
    acc[5] += w0 * bfhi(v0.z) + w1 * bfhi(v1.z);
    acc[6] += w0 * bflo(v0.w) + w1 * bflo(v1.w);
    acc[7] += w0 * bfhi(v0.w) + w1 * bfhi(v1.w);
  }
  if (e < end) {
    int s0 = sidx[e];
    const __hip_bfloat16* p0 = QKV + (size_t)s0 * 1536 + lane * 8;
    uint4 k0 = *(const uint4*)p0;
    uint4 v0 = *(const uint4*)(p0 + 1024);
    float d0 = q[0] * bflo(k0.x) + q[1] * bfhi(k0.x) + q[2] * bflo(k0.y) + q[3] * bfhi(k0.y)
             + q[4] * bflo(k0.z) + q[5] * bfhi(k0.z) + q[6] * bflo(k0.w) + q[7] * bfhi(k0.w);
    d0 += __shfl_xor(d0, 1);
    d0 += __shfl_xor(d0, 2);
    d0 += __shfl_xor(d0, 4);
    float w0 = expf(d0 * 0.125f);
    ssum += w0;
    acc[0] += w0 * bflo(v0.x); acc[1] += w0 * bfhi(v0.x);
    acc[2] += w0 * bflo(v0.y); acc[3] += w0 * bfhi(v0.y);
    acc[4] += w0 * bflo(v0.z); acc[5] += w0 * bfhi(v0.z);
    acc[6] += w0 * bflo(v0.w); acc[7] += w0 * bfhi(v0.w);
  }
  const float inv = (end > start) ? 1.0f / ssum : 0.f;
  union { ushort4 u[2]; __hip_bfloat16 h[8]; } o;
#pragma unroll
  for (int j = 0; j < 8; ++j) o.h[j] = __float2bfloat16(acc[j] * inv);
  // xp layout: lane holds k=lane*8..+7 -> c=lane>>2, q=lane&3, lp=q*16+(r&15)
  int t = r >> 4, c = lane >> 2, qq = lane & 3, lp = qq * 16 + (r & 15);
  __hip_bfloat16* dst = aggp + (size_t)t * 8192 + c * 512 + lp * 8;
  *(ushort4*)dst = o.u[0];
  *(ushort4*)(dst + 4) = o.u[1];
}

// ---------------------------------------------------------------------------
// Launch
// ---------------------------------------------------------------------------
extern "C" void kernel_launch(void* const* d_in, const int* in_sizes, int n_in,
                              void* d_out, int out_size, void* d_ws, size_t ws_size,
                              hipStream_t stream) {
  const float* x    = (const float*)d_in[0];
  const int*   eidx = (const int*)d_in[1];
  const float* Wk   = (const float*)d_in[2];
  const float* bk   = (const float*)d_in[3];
  const float* Wq   = (const float*)d_in[4];
  const float* bq   = (const float*)d_in[5];
  const float* Wv   = (const float*)d_in[6];
  const float* bv   = (const float*)d_in[7];
  const float* Wff  = (const float*)d_in[8];
  const float* bff  = (const float*)d_in[9];
  float* out = (float*)d_out;

  const int N_ = in_sizes[0] / DMODEL;   // 25000
  const int M_ = in_sizes[1] / 2;        // 150000
  const int* senders = eidx;             // edge_index[0]
  const int* recv    = eidx + M_;        // edge_index[1]

  const int T16 = (N_ + 15) / 16;        // 16-row tiles
  const int Q4  = (T16 + 3) / 4;         // 64-row quads (= grid of gemm_quad)
  const int Npad = Q4 * 64;

  // workspace: xp | QKVb | aggp | Wp_qkv | Wp_ff | bqkv | ints
  __hip_bfloat16* xp    = (__hip_bfloat16*)d_ws;
  __hip_bfloat16* QKVb  = xp + (size_t)Npad * DMODEL;
  __hip_bfloat16* aggp  = QKVb + (size_t)N_ * 1536;
  __hip_bfloat16* Wp_qkv = aggp + (size_t)Npad * DMODEL;
  __hip_bfloat16* Wp_ff  = Wp_qkv + (size_t)24 * 32768;
  float* bqkv = (float*)(Wp_ff + (size_t)8 * 32768);
  int* deg    = (int*)(bqkv + 1536);
  int* offs   = deg + N_;
  int* cursor = offs + N_ + 1;
  int* sidx   = cursor + N_;
  int* bsum   = sidx + M_;
  int* bbase  = bsum + 64;

  const int nblk = (N_ + 1023) / 1024;   // <=64 for single-wave mid scan

  // conversions / permutes
  cvtp_kernel<<<(Npad * 64 + 255) / 256, 256, 0, stream>>>(x, xp, N_, Npad);
  wp_kernel<<<dim3(16, 32), 256, 0, stream>>>(Wk, Wq, Wv, Wff, Wp_qkv, Wp_ff);
  bias_kernel<<<6, 256, 0, stream>>>(bk, bq, bv, bqkv);

  // CSR build
  hipMemsetAsync(deg, 0, N_ * sizeof(int), stream);
  hist_kernel<<<(M_ + 255) / 256, 256, 0, stream>>>(recv, deg, M_);
  scan_block<<<nblk, 256, 0, stream>>>(deg, offs, bsum, N_);
  scan_mid<<<1, 64, 0, stream>>>(bsum, bbase, nblk, offs, N_);
  scan_add<<<(N_ + 255) / 256, 256, 0, stream>>>(offs, bbase, cursor, N_);
  fill_kernel<<<(M_ + 255) / 256, 256, 0, stream>>>(senders, recv, cursor, sidx, M_);

  // fused QKV projection: one block per quad, A-in-LDS, W streamed via L2
  gemm_quad<true, 12><<<Q4, 512, 0, stream>>>(xp, Wp_qkv, bqkv, QKVb, N_, 1536);

  // fused single-pass edge softmax + aggregate (writes aggp in xp layout)
  attn_kernel<<<(N_ + 3) / 4, 256, 0, stream>>>(QKVb, sidx, offs, aggp, N_);

  // output projection
  gemm_quad<false, 4><<<Q4, 512, 0, stream>>>(aggp, Wp_ff, bff, out, N_, DMODEL);
}

// Round 5
// 300.918 us; speedup vs baseline: 1.8581x; 1.4751x over previous
//
#include <hip/hip_runtime.h>
#include <hip/hip_bf16.h>

#define DMODEL 512   // D = H*DK = H*DV = 512

typedef __attribute__((ext_vector_type(8))) short bf16x8;
typedef __attribute__((ext_vector_type(4))) float f32x4;

__device__ inline void gload_lds16(const void* g, void* s) {
  __builtin_amdgcn_global_load_lds((const __attribute__((address_space(1))) void*)g,
                                   (__attribute__((address_space(3))) void*)s, 16, 0, 0);
}

__device__ inline float bflo(unsigned u) {
  union { float f; unsigned u; } c; c.u = u << 16; return c.f;
}
__device__ inline float bfhi(unsigned u) {
  union { float f; unsigned u; } c; c.u = u & 0xffff0000u; return c.f;
}

// ---------------------------------------------------------------------------
// Quad-persistent bf16 MFMA GEMM, W-streamed.
// Block = one 64-row quad: A-quad (64 KB, fragment-linear xp layout) staged to
// LDS ONCE (single barrier), then 8 waves free-run. W streams from L2/L3
// (round-0 FETCH ~= A alone proves W never touches HBM).
// LEDGER (counter-verified):
//  R1: NT stores on 2B/lane epilogue -> partial-line RMW, 4.5x WRITE. Plain only.
//  R2: 16x-unrolled c-loop + 4 rotating b-buffer sets -> spills (symmetric
//      +150MB FETCH/WRITE scratch traffic). Depth must NOT come from live regs.
//  R3/R4: container failed twice on identical macro-pipeline source -> suspect
//      hipcc choking on _Pragma-in-macro; this is the same schedule macro-free.
//  R0 residual: ~3.3kcy stall per c-iter >> HW latency. Theory: all blocks run
//      the identical stripe/c schedule in lock-step -> ~50 blocks/XCD hit the
//      SAME 1KB of W simultaneously -> few L2 channels serve everything.
// THIS ROUND: (a) per-block rotation of c-phase (roff=q&15) and group order
// (desync the herd across 16*NG distinct address streams; only changes fp
// summation order); (b) copy-free ping-pong bA/bB prefetch in a c+=2 loop
// (no per-iter vmcnt(0) drain; counted waits). ~110 live VGPR, no spills.
// ---------------------------------------------------------------------------
template <bool OUT_BF16, int NT>
__global__ __launch_bounds__(512, 4)
void gemm_quad(const __hip_bfloat16* __restrict__ Ap,   // xp layout, 32768/quad
               const __hip_bfloat16* __restrict__ Wp,   // [stripe][c][n][lane][8]
               const float* __restrict__ bias, void* __restrict__ Cv,
               int Nrows, int ncols) {
  __shared__ __align__(16) short sA[32768];   // 64 KB: one quad of A
  const int tid = threadIdx.x;
  const int lane = tid & 63, w = tid >> 6;
  const int q = blockIdx.x;
  const __hip_bfloat16* Aq = Ap + (size_t)q * 32768;

#pragma unroll
  for (int i = 0; i < 8; ++i)
    gload_lds16(Aq + (size_t)(i * 512 + tid) * 8, &sA[(i * 512 + tid) * 8]);
  __syncthreads();

  const int l15 = lane & 15, lq = lane >> 4;
  const int roff = q & 15;                 // per-block K-phase rotation
  constexpr int NG = NT / 4;

#pragma unroll 1
  for (int gs0 = 0; gs0 < NG; ++gs0) {
    int gs = gs0 + (q % NG); if (gs >= NG) gs -= NG;   // per-block group rotation
    const int ntb = w * NT + gs * 4;
    const int stripe = w * NG + gs;
    const __hip_bfloat16* Wb = Wp + (size_t)stripe * 32768 + lane * 8;
    f32x4 acc[4][4] = {};
    bf16x8 bA0, bA1, bA2, bA3, bB0, bB1, bB2, bB3;

    // prologue: phase 0 -> bA
    {
      const int cc = roff;
      bA0 = *(const bf16x8*)(Wb + (size_t)(cc * 4 + 0) * 512);
      bA1 = *(const bf16x8*)(Wb + (size_t)(cc * 4 + 1) * 512);
      bA2 = *(const bf16x8*)(Wb + (size_t)(cc * 4 + 2) * 512);
      bA3 = *(const bf16x8*)(Wb + (size_t)(cc * 4 + 3) * 512);
    }

#pragma unroll 1
    for (int c = 0; c < 16; c += 2) {
      // prefetch phase c+1 -> bB (always valid: c+1 <= 15)
      {
        const int cc = (c + 1 + roff) & 15;
        bB0 = *(const bf16x8*)(Wb + (size_t)(cc * 4 + 0) * 512);
        bB1 = *(const bf16x8*)(Wb + (size_t)(cc * 4 + 1) * 512);
        bB2 = *(const bf16x8*)(Wb + (size_t)(cc * 4 + 2) * 512);
        bB3 = *(const bf16x8*)(Wb + (size_t)(cc * 4 + 3) * 512);
      }
      // compute phase c with bA
      {
        const int cc = (c + roff) & 15;
#pragma unroll
        for (int m = 0; m < 4; ++m) {
          bf16x8 af = *(const bf16x8*)&sA[(m * 16 + cc) * 512 + lane * 8];
          acc[m][0] = __builtin_amdgcn_mfma_f32_16x16x32_bf16(af, bA0, acc[m][0], 0, 0, 0);
          acc[m][1] = __builtin_amdgcn_mfma_f32_16x16x32_bf16(af, bA1, acc[m][1], 0, 0, 0);
          acc[m][2] = __builtin_amdgcn_mfma_f32_16x16x32_bf16(af, bA2, acc[m][2], 0, 0, 0);
          acc[m][3] = __builtin_amdgcn_mfma_f32_16x16x32_bf16(af, bA3, acc[m][3], 0, 0, 0);
        }
      }
      // prefetch phase c+2 -> bA (skip on last iteration; uniform branch)
      if (c + 2 < 16) {
        const int cc = (c + 2 + roff) & 15;
        bA0 = *(const bf16x8*)(Wb + (size_t)(cc * 4 + 0) * 512);
        bA1 = *(const bf16x8*)(Wb + (size_t)(cc * 4 + 1) * 512);
        bA2 = *(const bf16x8*)(Wb + (size_t)(cc * 4 + 2) * 512);
        bA3 = *(const bf16x8*)(Wb + (size_t)(cc * 4 + 3) * 512);
      }
      // compute phase c+1 with bB
      {
        const int cc = (c + 1 + roff) & 15;
#pragma unroll
        for (int m = 0; m < 4; ++m) {
          bf16x8 af = *(const bf16x8*)&sA[(m * 16 + cc) * 512 + lane * 8];
          acc[m][0] = __builtin_amdgcn_mfma_f32_16x16x32_bf16(af, bB0, acc[m][0], 0, 0, 0);
          acc[m][1] = __builtin_amdgcn_mfma_f32_16x16x32_bf16(af, bB1, acc[m][1], 0, 0, 0);
          acc[m][2] = __builtin_amdgcn_mfma_f32_16x16x32_bf16(af, bB2, acc[m][2], 0, 0, 0);
          acc[m][3] = __builtin_amdgcn_mfma_f32_16x16x32_bf16(af, bB3, acc[m][3], 0, 0, 0);
        }
      }
    }

    // epilogue: C/D layout col=lane&15, row=quad*4+reg. PLAIN stores: 32B/16-
    // lane segments merge to full lines in L2 (R0 WRITE ~= ideal 77MB).
#pragma unroll
    for (int m = 0; m < 4; ++m) {
      int rowb = q * 64 + m * 16;
#pragma unroll
      for (int n = 0; n < 4; ++n) {
        int col = (ntb + n) * 16 + l15;
        float bv = bias[col];
#pragma unroll
        for (int i = 0; i < 4; ++i) {
          int row = rowb + lq * 4 + i;
          if (row < Nrows) {
            float v = acc[m][n][i] + bv;
            if (OUT_BF16)
              ((__hip_bfloat16*)Cv)[(size_t)row * ncols + col] = __float2bfloat16(v);
            else
              ((float*)Cv)[(size_t)row * ncols + col] = v;
          }
        }
      }
    }
  }
}

// ---------------------------------------------------------------------------
// fp32 x -> bf16 xp permute: xp[t][c][lp][8], lp = q*16 + (r&15). Zero-pads.
// ---------------------------------------------------------------------------
__global__ void cvtp_kernel(const float* __restrict__ x, __hip_bfloat16* __restrict__ xp,
                            int Nrows, int NpadRows) {
  int tid = blockIdx.x * 256 + threadIdx.x;
  int r = tid >> 6, kb = tid & 63;
  if (r >= NpadRows) return;
  int t = r >> 4, c = kb >> 2, qq = kb & 3, lp = qq * 16 + (r & 15);
  __hip_bfloat16* dst = xp + (size_t)t * 8192 + c * 512 + lp * 8;
  union { ushort4 u[2]; __hip_bfloat16 h[8]; } o;
#pragma unroll
  for (int j = 0; j < 8; ++j) o.h[j] = __float2bfloat16(0.f);
  if (r < Nrows) {
    float4 v0 = *(const float4*)(x + (size_t)r * DMODEL + kb * 8);
    float4 v1 = *(const float4*)(x + (size_t)r * DMODEL + kb * 8 + 4);
    o.h[0] = __float2bfloat16(v0.x); o.h[1] = __float2bfloat16(v0.y);
    o.h[2] = __float2bfloat16(v0.z); o.h[3] = __float2bfloat16(v0.w);
    o.h[4] = __float2bfloat16(v1.x); o.h[5] = __float2bfloat16(v1.y);
    o.h[6] = __float2bfloat16(v1.z); o.h[7] = __float2bfloat16(v1.w);
  }
  *(ushort4*)dst = o.u[0];
  *(ushort4*)(dst + 4) = o.u[1];
}

// ---------------------------------------------------------------------------
// Weight permute: Wp[stripe][c][n][l][8] with stripe covering 4 n-tiles
// (col = (stripe*4+n)*16 + (l&15), k = c*32 + (l>>4)*8 + j). The 4 tiles of
// one c are CONTIGUOUS (4KB) so gemm's per-c loads share one base address.
// Stripes 0-23 -> Wp_qkv, 24-31 -> Wp_ff.
// ---------------------------------------------------------------------------
__global__ __launch_bounds__(256)
void wp_kernel(const float* __restrict__ Wk, const float* __restrict__ Wq,
               const float* __restrict__ Wv, const float* __restrict__ Wff,
               __hip_bfloat16* __restrict__ Wp_qkv, __hip_bfloat16* __restrict__ Wp_ff) {
  int c = blockIdx.x;        // 0..15
  int S = blockIdx.y;        // 0..31
  const float* W; __hip_bfloat16* dst;
  if (S < 8)       { W = Wk;  dst = Wp_qkv + (size_t)S * 32768; }
  else if (S < 16) { W = Wq;  dst = Wp_qkv + (size_t)S * 32768; }
  else if (S < 24) { W = Wv;  dst = Wp_qkv + (size_t)S * 32768; }
  else             { W = Wff; dst = Wp_ff + (size_t)(S - 24) * 32768; }
  int colbase = (S & 7) * 64;
  __shared__ float tile[32][64];
  for (int idx = threadIdx.x; idx < 2048; idx += 256) {
    int r = idx >> 6, col = idx & 63;
    tile[r][col] = W[(size_t)(c * 32 + r) * DMODEL + colbase + col];
  }
  __syncthreads();
  int n = threadIdx.x >> 6, l = threadIdx.x & 63;
  union { ushort4 u[2]; __hip_bfloat16 h[8]; } o;
#pragma unroll
  for (int j = 0; j < 8; ++j)
    o.h[j] = __float2bfloat16(tile[(l >> 4) * 8 + j][n * 16 + (l & 15)]);
  __hip_bfloat16* p = dst + ((size_t)(c * 4 + n) * 64 + l) * 8;
  *(ushort4*)p = o.u[0];
  *(ushort4*)(p + 4) = o.u[1];
}

// bias concat [bk | bq | bv]
__global__ void bias_kernel(const float* __restrict__ bk, const float* __restrict__ bq,
                            const float* __restrict__ bv, float* __restrict__ o) {
  int i = blockIdx.x * 256 + threadIdx.x;
  if (i < 512) o[i] = bk[i];
  else if (i < 1024) o[i] = bq[i - 512];
  else if (i < 1536) o[i] = bv[i - 1024];
}

// ---------------------------------------------------------------------------
// CSR build: histogram + parallel 3-phase scan + fill (stores SENDER directly)
// ---------------------------------------------------------------------------
__global__ void hist_kernel(const int* __restrict__ recv, int* __restrict__ deg, int M_) {
  int m = blockIdx.x * 256 + threadIdx.x;
  if (m < M_) atomicAdd(&deg[recv[m]], 1);
}

__global__ __launch_bounds__(256)
void scan_block(const int* __restrict__ deg, int* __restrict__ offs,
                int* __restrict__ bsum, int n) {
  __shared__ int sd[256];
  const int t = threadIdx.x;
  const int base = blockIdx.x * 1024;
  int v[4], s = 0;
#pragma unroll
  for (int j = 0; j < 4; ++j) {
    int idx = base + t * 4 + j;
    v[j] = (idx < n) ? deg[idx] : 0;
    s += v[j];
  }
  sd[t] = s;
  __syncthreads();
  for (int off = 1; off < 256; off <<= 1) {
    int x = (t >= off) ? sd[t - off] : 0;
    __syncthreads();
    sd[t] += x;
    __syncthreads();
  }
  int run = sd[t] - s;
#pragma unroll
  for (int j = 0; j < 4; ++j) {
    int idx = base + t * 4 + j;
    if (idx < n) offs[idx] = run;
    run += v[j];
  }
  if (t == 255) bsum[blockIdx.x] = sd[255];
}

__global__ void scan_mid(const int* __restrict__ bsum, int* __restrict__ bbase,
                         int nb, int* __restrict__ offs, int n) {
  int t = threadIdx.x;
  int x = (t < nb) ? bsum[t] : 0;
  int v = x;
  for (int off = 1; off < 64; off <<= 1) {
    int y = __shfl_up(v, off);
    if (t >= off) v += y;
  }
  if (t < nb) bbase[t] = v - x;
  if (t == nb - 1) offs[n] = v;
}

__global__ void scan_add(int* __restrict__ offs, const int* __restrict__ bbase,
                         int* __restrict__ cursor, int n) {
  int i = blockIdx.x * 256 + threadIdx.x;
  if (i < n) {
    int o = offs[i] + bbase[i >> 10];
    offs[i] = o;
    cursor[i] = o;
  }
}

__global__ void fill_kernel(const int* __restrict__ senders, const int* __restrict__ recv,
                            int* __restrict__ cursor, int* __restrict__ sidx, int M_) {
  int m = blockIdx.x * 256 + threadIdx.x;
  if (m < M_) {
    int pos = atomicAdd(&cursor[recv[m]], 1);
    sidx[pos] = senders[m];
  }
}

// ---------------------------------------------------------------------------
// Fused edge attention + aggregate, single pass, one wave per receiver.
// QKV row-major [K|Q|V] stride 1536 bf16. agg written directly in xp layout.
// ---------------------------------------------------------------------------
__global__ __launch_bounds__(256)
void attn_kernel(const __hip_bfloat16* __restrict__ QKV, const int* __restrict__ sidx,
                 const int* __restrict__ offs, __hip_bfloat16* __restrict__ aggp, int n) {
  const int lane = threadIdx.x & 63;
  const int wid  = threadIdx.x >> 6;
  const int r = blockIdx.x * 4 + wid;
  if (r >= n) return;
  const int start = offs[r];
  const int end   = offs[r + 1];

  uint4 qr = *(const uint4*)(QKV + (size_t)r * 1536 + 512 + lane * 8);
  float q[8] = {bflo(qr.x), bfhi(qr.x), bflo(qr.y), bfhi(qr.y),
                bflo(qr.z), bfhi(qr.z), bflo(qr.w), bfhi(qr.w)};

  float ssum = 0.f;
  float acc[8] = {};
  int e = start;
  for (; e + 2 <= end; e += 2) {
    int s0 = sidx[e], s1 = sidx[e + 1];
    const __hip_bfloat16* p0 = QKV + (size_t)s0 * 1536 + lane * 8;
    const __hip_bfloat16* p1 = QKV + (size_t)s1 * 1536 + lane * 8;
    uint4 k0 = *(const uint4*)p0;
    uint4 v0 = *(const uint4*)(p0 + 1024);
    uint4 k1 = *(const uint4*)p1;
    uint4 v1 = *(const uint4*)(p1 + 1024);
    float d0 = q[0] * bflo(k0.x) + q[1] * bfhi(k0.x) + q[2] * bflo(k0.y) + q[3] * bfhi(k0.y)
             + q[4] * bflo(k0.z) + q[5] * bfhi(k0.z) + q[6] * bflo(k0.w) + q[7] * bfhi(k0.w);
    float d1 = q[0] * bflo(k1.x) + q[1] * bfhi(k1.x) + q[2] * bflo(k1.y) + q[3] * bfhi(k1.y)
             + q[4] * bflo(k1.z) + q[5] * bfhi(k1.z) + q[6] * bflo(k1.w) + q[7] * bfhi(k1.w);
    d0 += __shfl_xor(d0, 1); d1 += __shfl_xor(d1, 1);
    d0 += __shfl_xor(d0, 2); d1 += __shfl_xor(d1, 2);
    d0 += __shfl_xor(d0, 4); d1 += __shfl_xor(d1, 4);
    float w0 = expf(d0 * 0.125f), w1 = expf(d1 * 0.125f);
    ssum += w0 + w1;
    acc[0] += w0 * bflo(v0.x) + w1 * bflo(v1.x);
    acc[1] += w0 * bfhi(v0.x) + w1 * bfhi(v1.x);
    acc[2] += w0 * bflo(v0.y) + w1 * bflo(v1.y);
    acc[3] += w0 * bfhi(v0.y) + w1 * bfhi(v1.y);
    acc[4] += w0 * bflo(v0.z) + w1 * bflo(v1.z);
    acc[5] += w0 * bfhi(v0.z) + w1 * bfhi(v1.z);
    acc[6] += w0 * bflo(v0.w) + w1 * bflo(v1.w);
    acc[7] += w0 * bfhi(v0.w) + w1 * bfhi(v1.w);
  }
  if (e < end) {
    int s0 = sidx[e];
    const __hip_bfloat16* p0 = QKV + (size_t)s0 * 1536 + lane * 8;
    uint4 k0 = *(const uint4*)p0;
    uint4 v0 = *(const uint4*)(p0 + 1024);
    float d0 = q[0] * bflo(k0.x) + q[1] * bfhi(k0.x) + q[2] * bflo(k0.y) + q[3] * bfhi(k0.y)
             + q[4] * bflo(k0.z) + q[5] * bfhi(k0.z) + q[6] * bflo(k0.w) + q[7] * bfhi(k0.w);
    d0 += __shfl_xor(d0, 1);
    d0 += __shfl_xor(d0, 2);
    d0 += __shfl_xor(d0, 4);
    float w0 = expf(d0 * 0.125f);
    ssum += w0;
    acc[0] += w0 * bflo(v0.x); acc[1] += w0 * bfhi(v0.x);
    acc[2] += w0 * bflo(v0.y); acc[3] += w0 * bfhi(v0.y);
    acc[4] += w0 * bflo(v0.z); acc[5] += w0 * bfhi(v0.z);
    acc[6] += w0 * bflo(v0.w); acc[7] += w0 * bfhi(v0.w);
  }
  const float inv = (end > start) ? 1.0f / ssum : 0.f;
  union { ushort4 u[2]; __hip_bfloat16 h[8]; } o;
#pragma unroll
  for (int j = 0; j < 8; ++j) o.h[j] = __float2bfloat16(acc[j] * inv);
  // xp layout: lane holds k=lane*8..+7 -> c=lane>>2, q=lane&3, lp=q*16+(r&15)
  int t = r >> 4, c = lane >> 2, qq = lane & 3, lp = qq * 16 + (r & 15);
  __hip_bfloat16* dst = aggp + (size_t)t * 8192 + c * 512 + lp * 8;
  *(ushort4*)dst = o.u[0];
  *(ushort4*)(dst + 4) = o.u[1];
}

// ---------------------------------------------------------------------------
// Launch
// ---------------------------------------------------------------------------
extern "C" void kernel_launch(void* const* d_in, const int* in_sizes, int n_in,
                              void* d_out, int out_size, void* d_ws, size_t ws_size,
                              hipStream_t stream) {
  const float* x    = (const float*)d_in[0];
  const int*   eidx = (const int*)d_in[1];
  const float* Wk   = (const float*)d_in[2];
  const float* bk   = (const float*)d_in[3];
  const float* Wq   = (const float*)d_in[4];
  const float* bq   = (const float*)d_in[5];
  const float* Wv   = (const float*)d_in[6];
  const float* bv   = (const float*)d_in[7];
  const float* Wff  = (const float*)d_in[8];
  const float* bff  = (const float*)d_in[9];
  float* out = (float*)d_out;

  const int N_ = in_sizes[0] / DMODEL;   // 25000
  const int M_ = in_sizes[1] / 2;        // 150000
  const int* senders = eidx;             // edge_index[0]
  const int* recv    = eidx + M_;        // edge_index[1]

  const int T16 = (N_ + 15) / 16;        // 16-row tiles
  const int Q4  = (T16 + 3) / 4;         // 64-row quads (= grid of gemm_quad)
  const int Npad = Q4 * 64;

  // workspace: xp | QKVb | aggp | Wp_qkv | Wp_ff | bqkv | ints
  __hip_bfloat16* xp    = (__hip_bfloat16*)d_ws;
  __hip_bfloat16* QKVb  = xp + (size_t)Npad * DMODEL;
  __hip_bfloat16* aggp  = QKVb + (size_t)N_ * 1536;
  __hip_bfloat16* Wp_qkv = aggp + (size_t)Npad * DMODEL;
  __hip_bfloat16* Wp_ff  = Wp_qkv + (size_t)24 * 32768;
  float* bqkv = (float*)(Wp_ff + (size_t)8 * 32768);
  int* deg    = (int*)(bqkv + 1536);
  int* offs   = deg + N_;
  int* cursor = offs + N_ + 1;
  int* sidx   = cursor + N_;
  int* bsum   = sidx + M_;
  int* bbase  = bsum + 64;

  const int nblk = (N_ + 1023) / 1024;   // <=64 for single-wave mid scan

  // conversions / permutes
  cvtp_kernel<<<(Npad * 64 + 255) / 256, 256, 0, stream>>>(x, xp, N_, Npad);
  wp_kernel<<<dim3(16, 32), 256, 0, stream>>>(Wk, Wq, Wv, Wff, Wp_qkv, Wp_ff);
  bias_kernel<<<6, 256, 0, stream>>>(bk, bq, bv, bqkv);

  // CSR build
  hipMemsetAsync(deg, 0, N_ * sizeof(int), stream);
  hist_kernel<<<(M_ + 255) / 256, 256, 0, stream>>>(recv, deg, M_);
  scan_block<<<nblk, 256, 0, stream>>>(deg, offs, bsum, N_);
  scan_mid<<<1, 64, 0, stream>>>(bsum, bbase, nblk, offs, N_);
  scan_add<<<(N_ + 255) / 256, 256, 0, stream>>>(offs, bbase, cursor, N_);
  fill_kernel<<<(M_ + 255) / 256, 256, 0, stream>>>(senders, recv, cursor, sidx, M_);

  // fused QKV projection: one block per quad, A-in-LDS, W streamed via L2
  gemm_quad<true, 12><<<Q4, 512, 0, stream>>>(xp, Wp_qkv, bqkv, QKVb, N_, 1536);

  // fused single-pass edge softmax + aggregate (writes aggp in xp layout)
  attn_kernel<<<(N_ + 3) / 4, 256, 0, stream>>>(QKVb, sidx, offs, aggp, N_);

  // output projection
  gemm_quad<false, 4><<<Q4, 512, 0, stream>>>(aggp, Wp_ff, bff, out, N_, DMODEL);
}